// Round 9
// baseline (562.625 us; speedup 1.0000x reference)
//
#include <hip/hip_runtime.h>
#include <hip/hip_bf16.h>
#include <math.h>

// GeometricNodeClassifier on MI355X — round 9 (bf16 gather tables, f32 math,
// matmul-before-aggregate, CSR aggregation, separable layer-0 table).
//
// Restructurings so far:
//  1. mean-aggregation commutes with the linear layer: Y = X @ [w_rel|w_root]
//     FIRST (dense GEMM), then aggregate 128-dim rows over edges.
//  2. GEMM K-loop register pipeline.
//  3. CSR build once; per-layer aggregation = per-node segmented sum (zero
//     atomics) fused with mean/bias/root/ELU epilogue.
//  4. Layer-0: x in 0..7 => <=512 distinct rows; aggregate from combo table.
//  5. 3-pass parallel scan (r4: single-block scan was 140us).
//  6. Aggregate unrolled x4 (4 gather rows in flight).
//  7. Separable layer-0 table: ptab(24 blk) + ytab(512 blk) replace the
//     8-block combo GEMM (r6 top dispatch, 75-177us).
//  8. count+combo merged.
//  9. r8 profile: aggregate x2 = 61us each @ 188MB FETCH, ~7.2 TB/s effective
//     gather -> byte-bound. Y/Yc stored as bf16 (RNE): halves gather traffic
//     and GEMM writes. Accumulation/activations/weights stay f32.
//     fill packs (src,combo) into one int2 store per edge.

#define N_NODES 50000
#define N_EDGES 800000
#define SCAN_NBLK ((N_NODES + 255) / 256)   // 196

__device__ __forceinline__ float eluf(float v) {
    return v > 0.0f ? v : expm1f(v);
}

__device__ __forceinline__ float b2f(unsigned short u) {
    union { unsigned int i; float f; } v; v.i = ((unsigned int)u) << 16; return v.f;
}
__device__ __forceinline__ unsigned short f2b(float f) {   // round-to-nearest-even
    union { float f; unsigned int i; } v; v.f = f;
    return (unsigned short)((v.i + 0x7FFFu + ((v.i >> 16) & 1u)) >> 16);
}

// ---------------- in-degree count + per-node combo id ----------------
__global__ __launch_bounds__(256) void count_combo_kernel(
        const int* __restrict__ tgt, const int* __restrict__ x,
        int* __restrict__ cnt, int* __restrict__ combo, int E) {
    int i = blockIdx.x * 256 + threadIdx.x;
    if (i < E) atomicAdd(&cnt[tgt[i]], 1);
    if (i < N_NODES)
        combo[i] = x[i * 3] * 64 + x[i * 3 + 1] * 8 + x[i * 3 + 2];
}

// ---------------- parallel exclusive scan ----------------
__global__ __launch_bounds__(256) void scan_part_kernel(const int* __restrict__ cnt,
        int* __restrict__ part) {
    int i = blockIdx.x * 256 + threadIdx.x;
    int v = (i < N_NODES) ? cnt[i] : 0;
    #pragma unroll
    for (int o = 32; o > 0; o >>= 1) v += __shfl_down(v, o, 64);
    __shared__ int ws[4];
    if ((threadIdx.x & 63) == 0) ws[threadIdx.x >> 6] = v;
    __syncthreads();
    if (threadIdx.x == 0) part[blockIdx.x] = ws[0] + ws[1] + ws[2] + ws[3];
}

__global__ __launch_bounds__(256) void scan_top_kernel(int* __restrict__ part) {
    __shared__ int tmp[256];
    int t = threadIdx.x;
    int v = (t < SCAN_NBLK) ? part[t] : 0;
    tmp[t] = v;
    __syncthreads();
    for (int o = 1; o < 256; o <<= 1) {
        int u = (t >= o) ? tmp[t - o] : 0;
        __syncthreads();
        tmp[t] += u;
        __syncthreads();
    }
    if (t < SCAN_NBLK) part[t] = tmp[t] - v;   // exclusive
}

__global__ __launch_bounds__(256) void scan_final_kernel(const int* __restrict__ cnt,
        const int* __restrict__ part, int* __restrict__ offsets, int* __restrict__ pos) {
    __shared__ int tmp[256];
    int i = blockIdx.x * 256 + threadIdx.x;
    int t = threadIdx.x;
    int v = (i < N_NODES) ? cnt[i] : 0;
    tmp[t] = v;
    __syncthreads();
    for (int o = 1; o < 256; o <<= 1) {
        int u = (t >= o) ? tmp[t - o] : 0;
        __syncthreads();
        tmp[t] += u;
        __syncthreads();
    }
    int excl = tmp[t] - v + part[blockIdx.x];
    if (i < N_NODES) { offsets[i] = excl; pos[i] = excl; }
    if (i == 0) offsets[N_NODES] = N_EDGES;
}

// ---------------- fill CSR: one packed int2 {src, combo[src]} per slot ----------
__global__ __launch_bounds__(256) void fill_kernel(const int* __restrict__ src,
        const int* __restrict__ tgt, const int* __restrict__ combo,
        int* __restrict__ pos, int2* __restrict__ oc) {
    int e = blockIdx.x * 256 + threadIdx.x;
    if (e < N_EDGES) {
        int s = src[e];
        int slot = atomicAdd(&pos[tgt[e]], 1);
        oc[slot] = make_int2(s, combo[s]);
    }
}

// ---------------- P tables: P[t*8+v][c] = emb_t[v] . [w_rel0|w_root0] seg t -------
__global__ __launch_bounds__(256) void ptab_kernel(const float* __restrict__ e0,
        const float* __restrict__ e1, const float* __restrict__ e2,
        const float* __restrict__ wrel, const float* __restrict__ wroot,
        float* __restrict__ P) {
    const int b = blockIdx.x;            // 0..23
    const int t = b >> 3, v = b & 7;
    const float* emb = (t == 0) ? e0 : (t == 1 ? e1 : e2);
    const float* erow = &emb[v * 200];
    const int c = threadIdx.x;           // 0..255
    const float* W = (c < 128) ? wrel : wroot;
    const float* Wp = &W[(size_t)(t * 200) * 128 + (c & 127)];
    __shared__ float es[200];
    for (int k = threadIdx.x; k < 200; k += 256) es[k] = erow[k];
    __syncthreads();
    float a0 = 0.f, a1 = 0.f;
    #pragma unroll 8
    for (int k = 0; k < 200; k += 2) {
        a0 = fmaf(es[k],     Wp[(size_t)k * 128],       a0);
        a1 = fmaf(es[k + 1], Wp[(size_t)(k + 1) * 128], a1);
    }
    P[(size_t)b * 256 + c] = a0 + a1;
}

// ---------------- Ycb[q] = bf16(P0[q>>6] + P1[(q>>3)&7] + P2[q&7]) ------------
__global__ __launch_bounds__(256) void ytab_kernel(const float* __restrict__ P,
        unsigned short* __restrict__ Ycb) {
    const int q = blockIdx.x;            // 0..511
    const int c = threadIdx.x;           // 0..255
    const float p0 = P[(size_t)(q >> 6) * 256 + c];
    const float p1 = P[(size_t)(8 + ((q >> 3) & 7)) * 256 + c];
    const float p2 = P[(size_t)(16 + (q & 7)) * 256 + c];
    Ycb[(size_t)q * 256 + c] = f2b(p0 + p1 + p2);
}

// ---------------- layer-0 aggregate from the bf16 combo table ----------------
__global__ __launch_bounds__(256) void aggregate0_kernel(
        const unsigned short* __restrict__ Ycb, const int2* __restrict__ oc,
        const int* __restrict__ combo, const int* __restrict__ offsets,
        const float* __restrict__ b, float* __restrict__ Xn) {
    int idx = blockIdx.x * 256 + threadIdx.x;
    int node = idx >> 5;
    int c = (idx & 31) * 4;
    if (node >= N_NODES) return;
    const int beg = offsets[node], end = offsets[node + 1];
    float ax = 0.f, ay = 0.f, az = 0.f, aw = 0.f;
    float gx = 0.f, gy = 0.f, gz = 0.f, gw = 0.f;
    int j = beg;
    for (; j + 3 < end; j += 4) {
        int q0 = oc[j].y, q1 = oc[j + 1].y, q2 = oc[j + 2].y, q3 = oc[j + 3].y;
        ushort4 u0 = *(const ushort4*)&Ycb[(size_t)q0 * 256 + c];
        ushort4 u1 = *(const ushort4*)&Ycb[(size_t)q1 * 256 + c];
        ushort4 u2 = *(const ushort4*)&Ycb[(size_t)q2 * 256 + c];
        ushort4 u3 = *(const ushort4*)&Ycb[(size_t)q3 * 256 + c];
        ax += b2f(u0.x) + b2f(u1.x); ay += b2f(u0.y) + b2f(u1.y);
        az += b2f(u0.z) + b2f(u1.z); aw += b2f(u0.w) + b2f(u1.w);
        gx += b2f(u2.x) + b2f(u3.x); gy += b2f(u2.y) + b2f(u3.y);
        gz += b2f(u2.z) + b2f(u3.z); gw += b2f(u2.w) + b2f(u3.w);
    }
    for (; j < end; ++j) {
        int q0 = oc[j].y;
        ushort4 u0 = *(const ushort4*)&Ycb[(size_t)q0 * 256 + c];
        ax += b2f(u0.x); ay += b2f(u0.y); az += b2f(u0.z); aw += b2f(u0.w);
    }
    float sx = ax + gx, sy = ay + gy, sz = az + gz, sw = aw + gw;
    const float inv = 1.0f / fmaxf((float)(end - beg), 1.0f);
    ushort4 ur = *(const ushort4*)&Ycb[(size_t)combo[node] * 256 + 128 + c];
    float4 bb = *(const float4*)&b[c];
    float4 o;
    o.x = eluf(fmaf(sx, inv, bb.x) + b2f(ur.x));
    o.y = eluf(fmaf(sy, inv, bb.y) + b2f(ur.y));
    o.z = eluf(fmaf(sz, inv, bb.z) + b2f(ur.z));
    o.w = eluf(fmaf(sw, inv, bb.w) + b2f(ur.w));
    *(float4*)&Xn[(size_t)node * 128 + c] = o;
}

// ---------------- layers 1/2 aggregate from bf16 Y ----------------
__global__ __launch_bounds__(256) void aggregate_kernel(
        const unsigned short* __restrict__ Yb, const int2* __restrict__ oc,
        const int* __restrict__ offsets,
        const float* __restrict__ b, float* __restrict__ Xn) {
    int idx = blockIdx.x * 256 + threadIdx.x;
    int node = idx >> 5;
    int c = (idx & 31) * 4;
    if (node >= N_NODES) return;
    const int beg = offsets[node], end = offsets[node + 1];
    float ax = 0.f, ay = 0.f, az = 0.f, aw = 0.f;
    float gx = 0.f, gy = 0.f, gz = 0.f, gw = 0.f;
    int j = beg;
    for (; j + 3 < end; j += 4) {
        int s0 = oc[j].x, s1 = oc[j + 1].x, s2 = oc[j + 2].x, s3 = oc[j + 3].x;
        ushort4 u0 = *(const ushort4*)&Yb[(size_t)s0 * 256 + c];
        ushort4 u1 = *(const ushort4*)&Yb[(size_t)s1 * 256 + c];
        ushort4 u2 = *(const ushort4*)&Yb[(size_t)s2 * 256 + c];
        ushort4 u3 = *(const ushort4*)&Yb[(size_t)s3 * 256 + c];
        ax += b2f(u0.x) + b2f(u1.x); ay += b2f(u0.y) + b2f(u1.y);
        az += b2f(u0.z) + b2f(u1.z); aw += b2f(u0.w) + b2f(u1.w);
        gx += b2f(u2.x) + b2f(u3.x); gy += b2f(u2.y) + b2f(u3.y);
        gz += b2f(u2.z) + b2f(u3.z); gw += b2f(u2.w) + b2f(u3.w);
    }
    for (; j < end; ++j) {
        int s0 = oc[j].x;
        ushort4 u0 = *(const ushort4*)&Yb[(size_t)s0 * 256 + c];
        ax += b2f(u0.x); ay += b2f(u0.y); az += b2f(u0.z); aw += b2f(u0.w);
    }
    float sx = ax + gx, sy = ay + gy, sz = az + gz, sw = aw + gw;
    const float inv = 1.0f / fmaxf((float)(end - beg), 1.0f);
    ushort4 ur = *(const ushort4*)&Yb[(size_t)node * 256 + 128 + c];
    float4 bb = *(const float4*)&b[c];
    float4 o;
    o.x = eluf(fmaf(sx, inv, bb.x) + b2f(ur.x));
    o.y = eluf(fmaf(sy, inv, bb.y) + b2f(ur.y));
    o.z = eluf(fmaf(sz, inv, bb.z) + b2f(ur.z));
    o.w = eluf(fmaf(sw, inv, bb.w) + b2f(ur.w));
    *(float4*)&Xn[(size_t)node * 128 + c] = o;
}

// ---------------- GEMM: Yb[:,y*128..] = bf16(A[M,128] @ B[128,128]) ------------
// BM=BN=128, BK=8, 256 threads, 8x8 register tile, register pipeline.
// A, B f32; acc f32; output rounded to bf16.
template<int K>
__global__ __launch_bounds__(256, 4) void gemm_rr(
        const float* __restrict__ A,
        const float* __restrict__ Brel, const float* __restrict__ Broot,
        unsigned short* __restrict__ Yb, int M) {
    __shared__ float As[8][132];   // transposed: As[kk][m]
    __shared__ float Bs[8][132];
    const float* __restrict__ B = (blockIdx.y == 0) ? Brel : Broot;
    const int m0 = blockIdx.x * 128;
    const int tid = threadIdx.x;
    const int am = tid & 127, ak = (tid >> 7) * 4;
    const int bc = (tid & 31) * 4, bk = tid >> 5;
    const int tr = (tid >> 4) * 8, tc = (tid & 15) * 8;
    const int arow = min(m0 + am, M - 1);
    float acc[8][8] = {};

    float4 av = *(const float4*)&A[(size_t)arow * K + ak];
    float4 bv = *(const float4*)&B[(size_t)bk * 128 + bc];

    for (int kt = 0; kt < K; kt += 8) {
        __syncthreads();
        As[ak + 0][am] = av.x;
        As[ak + 1][am] = av.y;
        As[ak + 2][am] = av.z;
        As[ak + 3][am] = av.w;
        *(float4*)&Bs[bk][bc] = bv;
        __syncthreads();
        if (kt + 8 < K) {
            av = *(const float4*)&A[(size_t)arow * K + kt + 8 + ak];
            bv = *(const float4*)&B[(size_t)(kt + 8 + bk) * 128 + bc];
        }
        #pragma unroll
        for (int kk = 0; kk < 8; ++kk) {
            float a[8], b[8];
            *(float4*)&a[0] = *(const float4*)&As[kk][tr];
            *(float4*)&a[4] = *(const float4*)&As[kk][tr + 4];
            *(float4*)&b[0] = *(const float4*)&Bs[kk][tc];
            *(float4*)&b[4] = *(const float4*)&Bs[kk][tc + 4];
            #pragma unroll
            for (int i = 0; i < 8; ++i)
                #pragma unroll
                for (int j = 0; j < 8; ++j)
                    acc[i][j] = fmaf(a[i], b[j], acc[i][j]);
        }
    }
    const int colofs = blockIdx.y * 128;
    #pragma unroll
    for (int i = 0; i < 8; ++i) {
        int row = m0 + tr + i;
        if (row < M) {
            uint4 w;
            w.x = (unsigned int)f2b(acc[i][0]) | ((unsigned int)f2b(acc[i][1]) << 16);
            w.y = (unsigned int)f2b(acc[i][2]) | ((unsigned int)f2b(acc[i][3]) << 16);
            w.z = (unsigned int)f2b(acc[i][4]) | ((unsigned int)f2b(acc[i][5]) << 16);
            w.w = (unsigned int)f2b(acc[i][6]) | ((unsigned int)f2b(acc[i][7]) << 16);
            *(uint4*)&Yb[(size_t)row * 256 + colofs + tc] = w;
        }
    }
}

// ---------------- output head: out = X @ w_out + b_out ----------------
__global__ __launch_bounds__(256) void out_kernel(const float* __restrict__ X,
        const float* __restrict__ W, const float* __restrict__ bo,
        float* __restrict__ out, int M) {
    __shared__ float Ws[128 * 32];
    const int tid = threadIdx.x;
    #pragma unroll
    for (int o = tid * 4; o < 4096; o += 1024)
        *(float4*)&Ws[o] = *(const float4*)&W[o];
    __syncthreads();
    const int row = blockIdx.x * 32 + (tid >> 3);
    const int col = (tid & 7) * 4;
    if (row >= M) return;
    float a0 = 0.f, a1 = 0.f, a2 = 0.f, a3 = 0.f;
    for (int k4 = 0; k4 < 32; ++k4) {
        float4 xv = *(const float4*)&X[(size_t)row * 128 + k4 * 4];
        float xa[4] = {xv.x, xv.y, xv.z, xv.w};
        #pragma unroll
        for (int j = 0; j < 4; ++j) {
            float4 wv = *(const float4*)&Ws[(k4 * 4 + j) * 32 + col];
            a0 = fmaf(xa[j], wv.x, a0);
            a1 = fmaf(xa[j], wv.y, a1);
            a2 = fmaf(xa[j], wv.z, a2);
            a3 = fmaf(xa[j], wv.w, a3);
        }
    }
    float4 bb = *(const float4*)&bo[col];
    *(float4*)&out[(size_t)row * 32 + col] =
        make_float4(a0 + bb.x, a1 + bb.y, a2 + bb.z, a3 + bb.w);
}

extern "C" void kernel_launch(void* const* d_in, const int* in_sizes, int n_in,
                              void* d_out, int out_size, void* d_ws, size_t ws_size,
                              hipStream_t stream) {
    const int* x        = (const int*)d_in[0];
    const int* ei       = (const int*)d_in[1];
    const float* e0     = (const float*)d_in[2];
    const float* e1     = (const float*)d_in[3];
    const float* e2     = (const float*)d_in[4];
    const float* w_rel0 = (const float*)d_in[5];
    const float* w_root0= (const float*)d_in[6];
    const float* b0     = (const float*)d_in[7];
    const float* w_rel1 = (const float*)d_in[8];
    const float* w_root1= (const float*)d_in[9];
    const float* b1     = (const float*)d_in[10];
    const float* w_rel2 = (const float*)d_in[11];
    const float* w_root2= (const float*)d_in[12];
    const float* b2     = (const float*)d_in[13];
    const float* w_out  = (const float*)d_in[14];
    const float* b_out  = (const float*)d_in[15];
    float* out = (float*)d_out;

    const int N = N_NODES, E = N_EDGES;
    // workspace layout (~58.7 MB, all offsets 16B-aligned)
    char* base = (char*)d_ws;
    float*          Xa   = (float*)base;                         // [N,128] f32, 25,600,000 B
    float*          P    = (float*)(base + 25600000);            // [24,256] f32, 24,576 B
    int2*           oc   = (int2*)(base + 25624576);             // [E] packed {src,combo}, 6,400,000 B
    unsigned short* Yb   = (unsigned short*)(base + 32024576);   // [N,256] bf16, 25,600,000 B
    unsigned short* Ycb  = (unsigned short*)(base + 57624576);   // [512,256] bf16, 262,144 B
    int*            cnt     = (int*)(base + 57886720);           // [N]
    int*            offsets = cnt + N;                           // [N+1]
    int*            pos     = offsets + N + 1;                   // [N]
    int*            combo   = pos + N;                           // [N]
    int*            part    = combo + N;                         // [SCAN_NBLK]

    const int* src = ei;
    const int* tgt = ei + E;

    // --- CSR build + combo ids ---
    hipMemsetAsync(cnt, 0, N * sizeof(int), stream);
    count_combo_kernel<<<(E + 255) / 256, 256, 0, stream>>>(tgt, x, cnt, combo, E);
    scan_part_kernel<<<SCAN_NBLK, 256, 0, stream>>>(cnt, part);
    scan_top_kernel<<<1, 256, 0, stream>>>(part);
    scan_final_kernel<<<SCAN_NBLK, 256, 0, stream>>>(cnt, part, offsets, pos);
    fill_kernel<<<(E + 255) / 256, 256, 0, stream>>>(src, tgt, combo, pos, oc);

    // --- layer-0 combo table (separable), bf16 ---
    ptab_kernel<<<24, 256, 0, stream>>>(e0, e1, e2, w_rel0, w_root0, P);
    ytab_kernel<<<512, 256, 0, stream>>>(P, Ycb);

    const int agg_grid = (N * 32 + 255) / 256;
    dim3 ggrid((N + 127) / 128, 2);

    // --- layer 0 ---
    aggregate0_kernel<<<agg_grid, 256, 0, stream>>>(Ycb, oc, combo, offsets, b0, Xa);

    // --- layers 1,2 ---
    gemm_rr<128><<<ggrid, 256, 0, stream>>>(Xa, w_rel1, w_root1, Yb, N);
    aggregate_kernel<<<agg_grid, 256, 0, stream>>>(Yb, oc, offsets, b1, Xa);
    gemm_rr<128><<<ggrid, 256, 0, stream>>>(Xa, w_rel2, w_root2, Yb, N);
    aggregate_kernel<<<agg_grid, 256, 0, stream>>>(Yb, oc, offsets, b2, Xa);

    out_kernel<<<(N + 31) / 32, 256, 0, stream>>>(Xa, w_out, b_out, out, N);
}

// Round 11
// 420.941 us; speedup vs baseline: 1.3366x; 1.3366x over previous
//
#include <hip/hip_runtime.h>
#include <hip/hip_bf16.h>
#include <math.h>

// GeometricNodeClassifier on MI355X — round 11 (= r10 resubmitted: GPU was
// unavailable, the isolation experiment never ran).
//
// f32 GEMM w/ proven store shape, bf16 gather plane via explicit convert,
// rel/root split, packed CSR payload.
//
// History: r4 652us -> r6 520 (parallel scan) -> r8 457 (separable layer-0
// table) -> r9 563 REGRESSION (bf16 gemm epilogue: gemm 144us, WRITE_SIZE 378MB
// vs 25.6MB actual — unexplained; f32 float4 512B-segment stores measured
// byte-exact in r6). This round isolates the variable: gemm writes f32 planes
// (r6/r8-proven epilogue shape), a tiny streaming conv kernel produces the
// bf16 rel plane for the gather (its WRITE_SIZE is the diagnostic for the r9
// store anomaly), aggregates gather bf16 (halved bytes = r8's measured
// bottleneck), root term streams f32.

#define N_NODES 50000
#define N_EDGES 800000
#define SCAN_NBLK ((N_NODES + 255) / 256)   // 196

__device__ __forceinline__ float eluf(float v) {
    return v > 0.0f ? v : expm1f(v);
}
__device__ __forceinline__ float b2f(unsigned short u) {
    union { unsigned int i; float f; } v; v.i = ((unsigned int)u) << 16; return v.f;
}
__device__ __forceinline__ unsigned short f2b(float f) {   // RNE
    union { float f; unsigned int i; } v; v.f = f;
    return (unsigned short)((v.i + 0x7FFFu + ((v.i >> 16) & 1u)) >> 16);
}

// ---------------- in-degree count + per-node combo id ----------------
__global__ __launch_bounds__(256) void count_combo_kernel(
        const int* __restrict__ tgt, const int* __restrict__ x,
        int* __restrict__ cnt, int* __restrict__ combo, int E) {
    int i = blockIdx.x * 256 + threadIdx.x;
    if (i < E) atomicAdd(&cnt[tgt[i]], 1);
    if (i < N_NODES)
        combo[i] = x[i * 3] * 64 + x[i * 3 + 1] * 8 + x[i * 3 + 2];
}

// ---------------- parallel exclusive scan ----------------
__global__ __launch_bounds__(256) void scan_part_kernel(const int* __restrict__ cnt,
        int* __restrict__ part) {
    int i = blockIdx.x * 256 + threadIdx.x;
    int v = (i < N_NODES) ? cnt[i] : 0;
    #pragma unroll
    for (int o = 32; o > 0; o >>= 1) v += __shfl_down(v, o, 64);
    __shared__ int ws[4];
    if ((threadIdx.x & 63) == 0) ws[threadIdx.x >> 6] = v;
    __syncthreads();
    if (threadIdx.x == 0) part[blockIdx.x] = ws[0] + ws[1] + ws[2] + ws[3];
}

__global__ __launch_bounds__(256) void scan_top_kernel(int* __restrict__ part) {
    __shared__ int tmp[256];
    int t = threadIdx.x;
    int v = (t < SCAN_NBLK) ? part[t] : 0;
    tmp[t] = v;
    __syncthreads();
    for (int o = 1; o < 256; o <<= 1) {
        int u = (t >= o) ? tmp[t - o] : 0;
        __syncthreads();
        tmp[t] += u;
        __syncthreads();
    }
    if (t < SCAN_NBLK) part[t] = tmp[t] - v;   // exclusive
}

__global__ __launch_bounds__(256) void scan_final_kernel(const int* __restrict__ cnt,
        const int* __restrict__ part, int* __restrict__ offsets, int* __restrict__ pos) {
    __shared__ int tmp[256];
    int i = blockIdx.x * 256 + threadIdx.x;
    int t = threadIdx.x;
    int v = (i < N_NODES) ? cnt[i] : 0;
    tmp[t] = v;
    __syncthreads();
    for (int o = 1; o < 256; o <<= 1) {
        int u = (t >= o) ? tmp[t - o] : 0;
        __syncthreads();
        tmp[t] += u;
        __syncthreads();
    }
    int excl = tmp[t] - v + part[blockIdx.x];
    if (i < N_NODES) { offsets[i] = excl; pos[i] = excl; }
    if (i == 0) offsets[N_NODES] = N_EDGES;
}

// ---------------- fill CSR: one packed int {src | combo<<16} per slot ----------
__global__ __launch_bounds__(256) void fill_kernel(const int* __restrict__ src,
        const int* __restrict__ tgt, const int* __restrict__ combo,
        int* __restrict__ pos, int* __restrict__ oc) {
    int e = blockIdx.x * 256 + threadIdx.x;
    if (e < N_EDGES) {
        int s = src[e];
        int slot = atomicAdd(&pos[tgt[e]], 1);
        oc[slot] = s | (combo[s] << 16);   // src < 2^16, combo < 2^9
    }
}

// ---------------- P tables: P[t*8+v][c] = emb_t[v] . [w_rel0|w_root0] seg t -------
__global__ __launch_bounds__(256) void ptab_kernel(const float* __restrict__ e0,
        const float* __restrict__ e1, const float* __restrict__ e2,
        const float* __restrict__ wrel, const float* __restrict__ wroot,
        float* __restrict__ P) {
    const int b = blockIdx.x;            // 0..23
    const int t = b >> 3, v = b & 7;
    const float* emb = (t == 0) ? e0 : (t == 1 ? e1 : e2);
    const float* erow = &emb[v * 200];
    const int c = threadIdx.x;           // 0..255
    const float* W = (c < 128) ? wrel : wroot;
    const float* Wp = &W[(size_t)(t * 200) * 128 + (c & 127)];
    __shared__ float es[200];
    for (int k = threadIdx.x; k < 200; k += 256) es[k] = erow[k];
    __syncthreads();
    float a0 = 0.f, a1 = 0.f;
    #pragma unroll 8
    for (int k = 0; k < 200; k += 2) {
        a0 = fmaf(es[k],     Wp[(size_t)k * 128],       a0);
        a1 = fmaf(es[k + 1], Wp[(size_t)(k + 1) * 128], a1);
    }
    P[(size_t)b * 256 + c] = a0 + a1;
}

// ---------------- Ycb[q] = bf16(P0[q>>6] + P1[(q>>3)&7] + P2[q&7]) ------------
__global__ __launch_bounds__(256) void ytab_kernel(const float* __restrict__ P,
        unsigned short* __restrict__ Ycb) {
    const int q = blockIdx.x;            // 0..511
    const int c = threadIdx.x;           // 0..255
    const float p0 = P[(size_t)(q >> 6) * 256 + c];
    const float p1 = P[(size_t)(8 + ((q >> 3) & 7)) * 256 + c];
    const float p2 = P[(size_t)(16 + (q & 7)) * 256 + c];
    Ycb[(size_t)q * 256 + c] = f2b(p0 + p1 + p2);
}

// ---------------- layer-0 aggregate from the bf16 combo table ----------------
__global__ __launch_bounds__(256) void aggregate0_kernel(
        const unsigned short* __restrict__ Ycb, const int* __restrict__ oc,
        const int* __restrict__ combo, const int* __restrict__ offsets,
        const float* __restrict__ b, float* __restrict__ Xn) {
    int idx = blockIdx.x * 256 + threadIdx.x;
    int node = idx >> 5;
    int c = (idx & 31) * 4;
    if (node >= N_NODES) return;
    const int beg = offsets[node], end = offsets[node + 1];
    float ax = 0.f, ay = 0.f, az = 0.f, aw = 0.f;
    float gx = 0.f, gy = 0.f, gz = 0.f, gw = 0.f;
    int j = beg;
    for (; j + 3 < end; j += 4) {
        int q0 = oc[j] >> 16, q1 = oc[j + 1] >> 16;
        int q2 = oc[j + 2] >> 16, q3 = oc[j + 3] >> 16;
        ushort4 u0 = *(const ushort4*)&Ycb[(size_t)q0 * 256 + c];
        ushort4 u1 = *(const ushort4*)&Ycb[(size_t)q1 * 256 + c];
        ushort4 u2 = *(const ushort4*)&Ycb[(size_t)q2 * 256 + c];
        ushort4 u3 = *(const ushort4*)&Ycb[(size_t)q3 * 256 + c];
        ax += b2f(u0.x) + b2f(u1.x); ay += b2f(u0.y) + b2f(u1.y);
        az += b2f(u0.z) + b2f(u1.z); aw += b2f(u0.w) + b2f(u1.w);
        gx += b2f(u2.x) + b2f(u3.x); gy += b2f(u2.y) + b2f(u3.y);
        gz += b2f(u2.z) + b2f(u3.z); gw += b2f(u2.w) + b2f(u3.w);
    }
    for (; j < end; ++j) {
        int q0 = oc[j] >> 16;
        ushort4 u0 = *(const ushort4*)&Ycb[(size_t)q0 * 256 + c];
        ax += b2f(u0.x); ay += b2f(u0.y); az += b2f(u0.z); aw += b2f(u0.w);
    }
    float sx = ax + gx, sy = ay + gy, sz = az + gz, sw = aw + gw;
    const float inv = 1.0f / fmaxf((float)(end - beg), 1.0f);
    ushort4 ur = *(const ushort4*)&Ycb[(size_t)combo[node] * 256 + 128 + c];
    float4 bb = *(const float4*)&b[c];
    float4 o;
    o.x = eluf(fmaf(sx, inv, bb.x) + b2f(ur.x));
    o.y = eluf(fmaf(sy, inv, bb.y) + b2f(ur.y));
    o.z = eluf(fmaf(sz, inv, bb.z) + b2f(ur.z));
    o.w = eluf(fmaf(sw, inv, bb.w) + b2f(ur.w));
    *(float4*)&Xn[(size_t)node * 128 + c] = o;
}

// ---------------- layers 1/2 aggregate: gather bf16 rel plane, stream f32 root ---
__global__ __launch_bounds__(256) void aggregate_kernel(
        const unsigned short* __restrict__ Ybrel, const float* __restrict__ Yroot,
        const int* __restrict__ oc, const int* __restrict__ offsets,
        const float* __restrict__ b, float* __restrict__ Xn) {
    int idx = blockIdx.x * 256 + threadIdx.x;
    int node = idx >> 5;
    int c = (idx & 31) * 4;
    if (node >= N_NODES) return;
    const int beg = offsets[node], end = offsets[node + 1];
    float ax = 0.f, ay = 0.f, az = 0.f, aw = 0.f;
    float gx = 0.f, gy = 0.f, gz = 0.f, gw = 0.f;
    int j = beg;
    for (; j + 3 < end; j += 4) {
        int s0 = oc[j] & 0xFFFF, s1 = oc[j + 1] & 0xFFFF;
        int s2 = oc[j + 2] & 0xFFFF, s3 = oc[j + 3] & 0xFFFF;
        ushort4 u0 = *(const ushort4*)&Ybrel[(size_t)s0 * 128 + c];
        ushort4 u1 = *(const ushort4*)&Ybrel[(size_t)s1 * 128 + c];
        ushort4 u2 = *(const ushort4*)&Ybrel[(size_t)s2 * 128 + c];
        ushort4 u3 = *(const ushort4*)&Ybrel[(size_t)s3 * 128 + c];
        ax += b2f(u0.x) + b2f(u1.x); ay += b2f(u0.y) + b2f(u1.y);
        az += b2f(u0.z) + b2f(u1.z); aw += b2f(u0.w) + b2f(u1.w);
        gx += b2f(u2.x) + b2f(u3.x); gy += b2f(u2.y) + b2f(u3.y);
        gz += b2f(u2.z) + b2f(u3.z); gw += b2f(u2.w) + b2f(u3.w);
    }
    for (; j < end; ++j) {
        int s0 = oc[j] & 0xFFFF;
        ushort4 u0 = *(const ushort4*)&Ybrel[(size_t)s0 * 128 + c];
        ax += b2f(u0.x); ay += b2f(u0.y); az += b2f(u0.z); aw += b2f(u0.w);
    }
    float sx = ax + gx, sy = ay + gy, sz = az + gz, sw = aw + gw;
    const float inv = 1.0f / fmaxf((float)(end - beg), 1.0f);
    float4 yr = *(const float4*)&Yroot[(size_t)node * 128 + c];
    float4 bb = *(const float4*)&b[c];
    float4 o;
    o.x = eluf(fmaf(sx, inv, bb.x) + yr.x);
    o.y = eluf(fmaf(sy, inv, bb.y) + yr.y);
    o.z = eluf(fmaf(sz, inv, bb.z) + yr.z);
    o.w = eluf(fmaf(sw, inv, bb.w) + yr.w);
    *(float4*)&Xn[(size_t)node * 128 + c] = o;
}

// ---------------- convert: f32 rel plane -> bf16 rel plane (diagnostic) ----------
__global__ __launch_bounds__(256) void conv_kernel(const float* __restrict__ Yf,
        unsigned short* __restrict__ Yb) {
    int i = blockIdx.x * 256 + threadIdx.x;      // over N*128/8 = 800000
    if (i >= N_NODES * 16) return;
    float4 a = ((const float4*)Yf)[(size_t)i * 2];
    float4 b = ((const float4*)Yf)[(size_t)i * 2 + 1];
    uint4 w;
    w.x = (unsigned int)f2b(a.x) | ((unsigned int)f2b(a.y) << 16);
    w.y = (unsigned int)f2b(a.z) | ((unsigned int)f2b(a.w) << 16);
    w.z = (unsigned int)f2b(b.x) | ((unsigned int)f2b(b.y) << 16);
    w.w = (unsigned int)f2b(b.z) | ((unsigned int)f2b(b.w) << 16);
    ((uint4*)Yb)[i] = w;
}

// ---------------- GEMM: rel/root planes = A[M,128] @ {Brel,Broot} (f32 out) ------
// BM=BN=128, BK=8, 256 threads, 8x8 register tile, register pipeline.
// Epilogue: r6/r8-proven 2x float4 per row (512B wave segments, byte-exact).
template<int K>
__global__ __launch_bounds__(256, 4) void gemm_rr(
        const float* __restrict__ A,
        const float* __restrict__ Brel, const float* __restrict__ Broot,
        float* __restrict__ Yrel, float* __restrict__ Yroot, int M) {
    __shared__ float As[8][132];   // transposed: As[kk][m]
    __shared__ float Bs[8][132];
    const float* __restrict__ B = (blockIdx.y == 0) ? Brel : Broot;
    float* __restrict__ Yp = (blockIdx.y == 0) ? Yrel : Yroot;
    const int m0 = blockIdx.x * 128;
    const int tid = threadIdx.x;
    const int am = tid & 127, ak = (tid >> 7) * 4;
    const int bc = (tid & 31) * 4, bk = tid >> 5;
    const int tr = (tid >> 4) * 8, tc = (tid & 15) * 8;
    const int arow = min(m0 + am, M - 1);
    float acc[8][8] = {};

    float4 av = *(const float4*)&A[(size_t)arow * K + ak];
    float4 bv = *(const float4*)&B[(size_t)bk * 128 + bc];

    for (int kt = 0; kt < K; kt += 8) {
        __syncthreads();
        As[ak + 0][am] = av.x;
        As[ak + 1][am] = av.y;
        As[ak + 2][am] = av.z;
        As[ak + 3][am] = av.w;
        *(float4*)&Bs[bk][bc] = bv;
        __syncthreads();
        if (kt + 8 < K) {
            av = *(const float4*)&A[(size_t)arow * K + kt + 8 + ak];
            bv = *(const float4*)&B[(size_t)(kt + 8 + bk) * 128 + bc];
        }
        #pragma unroll
        for (int kk = 0; kk < 8; ++kk) {
            float a[8], b[8];
            *(float4*)&a[0] = *(const float4*)&As[kk][tr];
            *(float4*)&a[4] = *(const float4*)&As[kk][tr + 4];
            *(float4*)&b[0] = *(const float4*)&Bs[kk][tc];
            *(float4*)&b[4] = *(const float4*)&Bs[kk][tc + 4];
            #pragma unroll
            for (int i = 0; i < 8; ++i)
                #pragma unroll
                for (int j = 0; j < 8; ++j)
                    acc[i][j] = fmaf(a[i], b[j], acc[i][j]);
        }
    }
    #pragma unroll
    for (int i = 0; i < 8; ++i) {
        int row = m0 + tr + i;
        if (row < M) {
            *(float4*)&Yp[(size_t)row * 128 + tc] =
                make_float4(acc[i][0], acc[i][1], acc[i][2], acc[i][3]);
            *(float4*)&Yp[(size_t)row * 128 + tc + 4] =
                make_float4(acc[i][4], acc[i][5], acc[i][6], acc[i][7]);
        }
    }
}

// ---------------- output head: out = X @ w_out + b_out ----------------
__global__ __launch_bounds__(256) void out_kernel(const float* __restrict__ X,
        const float* __restrict__ W, const float* __restrict__ bo,
        float* __restrict__ out, int M) {
    __shared__ float Ws[128 * 32];
    const int tid = threadIdx.x;
    #pragma unroll
    for (int o = tid * 4; o < 4096; o += 1024)
        *(float4*)&Ws[o] = *(const float4*)&W[o];
    __syncthreads();
    const int row = blockIdx.x * 32 + (tid >> 3);
    const int col = (tid & 7) * 4;
    if (row >= M) return;
    float a0 = 0.f, a1 = 0.f, a2 = 0.f, a3 = 0.f;
    for (int k4 = 0; k4 < 32; ++k4) {
        float4 xv = *(const float4*)&X[(size_t)row * 128 + k4 * 4];
        float xa[4] = {xv.x, xv.y, xv.z, xv.w};
        #pragma unroll
        for (int j = 0; j < 4; ++j) {
            float4 wv = *(const float4*)&Ws[(k4 * 4 + j) * 32 + col];
            a0 = fmaf(xa[j], wv.x, a0);
            a1 = fmaf(xa[j], wv.y, a1);
            a2 = fmaf(xa[j], wv.z, a2);
            a3 = fmaf(xa[j], wv.w, a3);
        }
    }
    float4 bb = *(const float4*)&bo[col];
    *(float4*)&out[(size_t)row * 32 + col] =
        make_float4(a0 + bb.x, a1 + bb.y, a2 + bb.z, a3 + bb.w);
}

extern "C" void kernel_launch(void* const* d_in, const int* in_sizes, int n_in,
                              void* d_out, int out_size, void* d_ws, size_t ws_size,
                              hipStream_t stream) {
    const int* x        = (const int*)d_in[0];
    const int* ei       = (const int*)d_in[1];
    const float* e0     = (const float*)d_in[2];
    const float* e1     = (const float*)d_in[3];
    const float* e2     = (const float*)d_in[4];
    const float* w_rel0 = (const float*)d_in[5];
    const float* w_root0= (const float*)d_in[6];
    const float* b0     = (const float*)d_in[7];
    const float* w_rel1 = (const float*)d_in[8];
    const float* w_root1= (const float*)d_in[9];
    const float* b1     = (const float*)d_in[10];
    const float* w_rel2 = (const float*)d_in[11];
    const float* w_root2= (const float*)d_in[12];
    const float* b2     = (const float*)d_in[13];
    const float* w_out  = (const float*)d_in[14];
    const float* b_out  = (const float*)d_in[15];
    float* out = (float*)d_out;

    const int N = N_NODES, E = N_EDGES;
    // workspace layout (~94 MB, 16B-aligned); F-plane rotation across layers:
    //  L1: gemm(F0 -> rel F2, root F1); conv(F2->H); agg(H,F1 -> F2)
    //  L2: gemm(F2 -> rel F0, root F1); conv(F0->H); agg(H,F1 -> F0); out(F0)
    char* base = (char*)d_ws;
    float*          F0  = (float*)base;                          // [N,128] f32
    float*          F1  = (float*)(base + 25600000);             // [N,128] f32
    float*          F2  = (float*)(base + 51200000);             // [N,128] f32
    unsigned short* H   = (unsigned short*)(base + 76800000);    // [N,128] bf16
    int*            oc  = (int*)(base + 89600000);               // [E] packed
    float*          P   = (float*)(base + 92800000);             // [24,256] f32
    unsigned short* Ycb = (unsigned short*)(base + 92824576);    // [512,256] bf16
    int*            cnt     = (int*)(base + 93086720);           // [N]
    int*            offsets = cnt + N;                           // [N+1]
    int*            pos     = offsets + N + 1;                   // [N]
    int*            combo   = pos + N;                           // [N]
    int*            part    = combo + N;                         // [SCAN_NBLK]

    const int* src = ei;
    const int* tgt = ei + E;

    // --- CSR build + combo ids ---
    hipMemsetAsync(cnt, 0, N * sizeof(int), stream);
    count_combo_kernel<<<(E + 255) / 256, 256, 0, stream>>>(tgt, x, cnt, combo, E);
    scan_part_kernel<<<SCAN_NBLK, 256, 0, stream>>>(cnt, part);
    scan_top_kernel<<<1, 256, 0, stream>>>(part);
    scan_final_kernel<<<SCAN_NBLK, 256, 0, stream>>>(cnt, part, offsets, pos);
    fill_kernel<<<(E + 255) / 256, 256, 0, stream>>>(src, tgt, combo, pos, oc);

    // --- layer-0 combo table (separable), bf16 ---
    ptab_kernel<<<24, 256, 0, stream>>>(e0, e1, e2, w_rel0, w_root0, P);
    ytab_kernel<<<512, 256, 0, stream>>>(P, Ycb);

    const int agg_grid = (N * 32 + 255) / 256;
    const int conv_grid = (N * 16 + 255) / 256;
    dim3 ggrid((N + 127) / 128, 2);

    // --- layer 0 -> F0 ---
    aggregate0_kernel<<<agg_grid, 256, 0, stream>>>(Ycb, oc, combo, offsets, b0, F0);

    // --- layer 1: F0 -> (F2 rel, F1 root) -> H -> F2 ---
    gemm_rr<128><<<ggrid, 256, 0, stream>>>(F0, w_rel1, w_root1, F2, F1, N);
    conv_kernel<<<conv_grid, 256, 0, stream>>>(F2, H);
    aggregate_kernel<<<agg_grid, 256, 0, stream>>>(H, F1, oc, offsets, b1, F2);

    // --- layer 2: F2 -> (F0 rel, F1 root) -> H -> F0 ---
    gemm_rr<128><<<ggrid, 256, 0, stream>>>(F2, w_rel2, w_root2, F0, F1, N);
    conv_kernel<<<conv_grid, 256, 0, stream>>>(F0, H);
    aggregate_kernel<<<agg_grid, 256, 0, stream>>>(H, F1, oc, offsets, b2, F0);

    out_kernel<<<(N + 31) / 32, 256, 0, stream>>>(F0, w_out, b_out, out, N);
}

// Round 13
// 351.592 us; speedup vs baseline: 1.6002x; 1.1972x over previous
//
#include <hip/hip_runtime.h>
#include <hip/hip_bf16.h>
#include <math.h>

// GeometricNodeClassifier on MI355X — round 13 (= r12 resubmitted: GPU was
// unavailable, MFMA experiment never ran; re-audited).
//
// MFMA GEMM, bf16 activations, f32 epilogue, CSR aggregation, separable
// layer-0 table.
//
// History: r4 652us -> r6 520 (parallel scan) -> r8 457 (separable layer-0
// table) -> r9 563 REGRESSION (bf16 gemm-epilogue stores: WRITE_SIZE 14x
// inflated) -> r11 421 (f32 gemm epilogue + bf16 gather plane via conv;
// isolation confirmed the r9 anomaly was the bf16 epilogue pattern).
// r11 profile: 2x gemm_rr 57us = top (37% of f32 vector peak, VALUBusy 40%,
// 3.2M LDS bank conflicts from stride-8 Bs reads, MfmaUtil 0).
// This round: matrix cores. mfma_f32_16x16x32_bf16, fragment-direct global
// loads (no LDS/barriers), weights pre-packed to fragment order, activations
// stored bf16 by the aggregates (absmax pinned at 2^-14 across f32/bf16
// rounds => bf16-level noise tolerated). Epilogue stays f32 scalar (r9 lesson).

#define N_NODES 50000
#define N_EDGES 800000
#define SCAN_NBLK ((N_NODES + 255) / 256)   // 196

typedef __attribute__((ext_vector_type(8))) short bf16x8;
typedef __attribute__((ext_vector_type(4))) float f32x4;

__device__ __forceinline__ float eluf(float v) {
    return v > 0.0f ? v : expm1f(v);
}
__device__ __forceinline__ float b2f(unsigned short u) {
    union { unsigned int i; float f; } v; v.i = ((unsigned int)u) << 16; return v.f;
}
__device__ __forceinline__ unsigned short f2b(float f) {   // RNE
    union { float f; unsigned int i; } v; v.f = f;
    return (unsigned short)((v.i + 0x7FFFu + ((v.i >> 16) & 1u)) >> 16);
}

// ---------------- in-degree count + per-node combo id ----------------
__global__ __launch_bounds__(256) void count_combo_kernel(
        const int* __restrict__ tgt, const int* __restrict__ x,
        int* __restrict__ cnt, int* __restrict__ combo, int E) {
    int i = blockIdx.x * 256 + threadIdx.x;
    if (i < E) atomicAdd(&cnt[tgt[i]], 1);
    if (i < N_NODES)
        combo[i] = x[i * 3] * 64 + x[i * 3 + 1] * 8 + x[i * 3 + 2];
}

// ---------------- parallel exclusive scan ----------------
__global__ __launch_bounds__(256) void scan_part_kernel(const int* __restrict__ cnt,
        int* __restrict__ part) {
    int i = blockIdx.x * 256 + threadIdx.x;
    int v = (i < N_NODES) ? cnt[i] : 0;
    #pragma unroll
    for (int o = 32; o > 0; o >>= 1) v += __shfl_down(v, o, 64);
    __shared__ int ws[4];
    if ((threadIdx.x & 63) == 0) ws[threadIdx.x >> 6] = v;
    __syncthreads();
    if (threadIdx.x == 0) part[blockIdx.x] = ws[0] + ws[1] + ws[2] + ws[3];
}

__global__ __launch_bounds__(256) void scan_top_kernel(int* __restrict__ part) {
    __shared__ int tmp[256];
    int t = threadIdx.x;
    int v = (t < SCAN_NBLK) ? part[t] : 0;
    tmp[t] = v;
    __syncthreads();
    for (int o = 1; o < 256; o <<= 1) {
        int u = (t >= o) ? tmp[t - o] : 0;
        __syncthreads();
        tmp[t] += u;
        __syncthreads();
    }
    if (t < SCAN_NBLK) part[t] = tmp[t] - v;   // exclusive
}

__global__ __launch_bounds__(256) void scan_final_kernel(const int* __restrict__ cnt,
        const int* __restrict__ part, int* __restrict__ offsets, int* __restrict__ pos) {
    __shared__ int tmp[256];
    int i = blockIdx.x * 256 + threadIdx.x;
    int t = threadIdx.x;
    int v = (i < N_NODES) ? cnt[i] : 0;
    tmp[t] = v;
    __syncthreads();
    for (int o = 1; o < 256; o <<= 1) {
        int u = (t >= o) ? tmp[t - o] : 0;
        __syncthreads();
        tmp[t] += u;
        __syncthreads();
    }
    int excl = tmp[t] - v + part[blockIdx.x];
    if (i < N_NODES) { offsets[i] = excl; pos[i] = excl; }
    if (i == 0) offsets[N_NODES] = N_EDGES;
}

// ---------------- fill CSR: one packed int {src | combo<<16} per slot ----------
__global__ __launch_bounds__(256) void fill_kernel(const int* __restrict__ src,
        const int* __restrict__ tgt, const int* __restrict__ combo,
        int* __restrict__ pos, int* __restrict__ oc) {
    int e = blockIdx.x * 256 + threadIdx.x;
    if (e < N_EDGES) {
        int s = src[e];
        int slot = atomicAdd(&pos[tgt[e]], 1);
        oc[slot] = s | (combo[s] << 16);   // src < 2^16, combo < 2^9
    }
}

// ---------------- P tables: P[t*8+v][c] = emb_t[v] . [w_rel0|w_root0] seg t -------
__global__ __launch_bounds__(256) void ptab_kernel(const float* __restrict__ e0,
        const float* __restrict__ e1, const float* __restrict__ e2,
        const float* __restrict__ wrel, const float* __restrict__ wroot,
        float* __restrict__ P) {
    const int b = blockIdx.x;            // 0..23
    const int t = b >> 3, v = b & 7;
    const float* emb = (t == 0) ? e0 : (t == 1 ? e1 : e2);
    const float* erow = &emb[v * 200];
    const int c = threadIdx.x;           // 0..255
    const float* W = (c < 128) ? wrel : wroot;
    const float* Wp = &W[(size_t)(t * 200) * 128 + (c & 127)];
    __shared__ float es[200];
    for (int k = threadIdx.x; k < 200; k += 256) es[k] = erow[k];
    __syncthreads();
    float a0 = 0.f, a1 = 0.f;
    #pragma unroll 8
    for (int k = 0; k < 200; k += 2) {
        a0 = fmaf(es[k],     Wp[(size_t)k * 128],       a0);
        a1 = fmaf(es[k + 1], Wp[(size_t)(k + 1) * 128], a1);
    }
    P[(size_t)b * 256 + c] = a0 + a1;
}

// ---------------- Ycb[q] = bf16(P0[q>>6] + P1[(q>>3)&7] + P2[q&7]) ------------
__global__ __launch_bounds__(256) void ytab_kernel(const float* __restrict__ P,
        unsigned short* __restrict__ Ycb) {
    const int q = blockIdx.x;            // 0..511
    const int c = threadIdx.x;           // 0..255
    const float p0 = P[(size_t)(q >> 6) * 256 + c];
    const float p1 = P[(size_t)(8 + ((q >> 3) & 7)) * 256 + c];
    const float p2 = P[(size_t)(16 + (q & 7)) * 256 + c];
    Ycb[(size_t)q * 256 + c] = f2b(p0 + p1 + p2);
}

// ---------------- pack weights to MFMA fragment order (bf16) ----------------
// Bp[mat][ks][ct][lane][i] = bf16(W[ks*32 + 8*(lane>>4) + i][ct*16 + (lane&15)])
// mat: 0=w_rel1 1=w_root1 2=w_rel2 3=w_root2. 128 blocks x 64 threads.
__global__ __launch_bounds__(64) void pack_kernel(const float* __restrict__ w1r,
        const float* __restrict__ w1t, const float* __restrict__ w2r,
        const float* __restrict__ w2t, unsigned short* __restrict__ Bp) {
    const int b = blockIdx.x, l = threadIdx.x;
    const int mat = b >> 5, ks = (b >> 3) & 3, ct = b & 7;
    const float* W = (mat == 0) ? w1r : (mat == 1) ? w1t : (mat == 2) ? w2r : w2t;
    const int col = ct * 16 + (l & 15);
    const int krow = ks * 32 + 8 * (l >> 4);
    unsigned short v[8];
    #pragma unroll
    for (int i = 0; i < 8; ++i)
        v[i] = f2b(W[(size_t)(krow + i) * 128 + col]);
    unsigned short* dst = &Bp[(size_t)((((mat * 4 + ks) * 8 + ct) * 64 + l) * 8)];
    #pragma unroll
    for (int i = 0; i < 8; ++i) dst[i] = v[i];
}

// ---------------- MFMA GEMM: {Yrel,Yroot}[M,128] = Xb[M,128] @ Wplane ----------
// 4 waves/block; wave handles 32 rows x 128 cols; fragment-direct global loads
// (A: 16B contiguous per lane; B: packed). f32 scalar epilogue (r9 lesson).
__global__ __launch_bounds__(256) void gemm_mfma(
        const unsigned short* __restrict__ Xb, const unsigned short* __restrict__ Bp,
        int matbase, float* __restrict__ Yrel, float* __restrict__ Yroot, int M) {
    const int plane = blockIdx.y;
    const unsigned short* Bpm = Bp + (size_t)(matbase + plane) * 4 * 8 * 64 * 8;
    float* __restrict__ Yp = plane ? Yroot : Yrel;
    const int w = threadIdx.x >> 6;
    const int l = threadIdx.x & 63;
    const int rbase = blockIdx.x * 128 + w * 32;
    const int arow0 = min(rbase + (l & 15), M - 1);
    const int arow1 = min(rbase + 16 + (l & 15), M - 1);
    const int kl = 8 * (l >> 4);
    f32x4 acc[2][8] = {};
    #pragma unroll
    for (int ks = 0; ks < 4; ++ks) {
        const int k0 = ks * 32 + kl;
        bf16x8 a0 = *(const bf16x8*)&Xb[(size_t)arow0 * 128 + k0];
        bf16x8 a1 = *(const bf16x8*)&Xb[(size_t)arow1 * 128 + k0];
        const unsigned short* bbase = Bpm + (size_t)ks * 8 * 64 * 8 + (size_t)l * 8;
        #pragma unroll
        for (int ct = 0; ct < 8; ++ct) {
            bf16x8 bf = *(const bf16x8*)&bbase[(size_t)ct * 64 * 8];
            acc[0][ct] = __builtin_amdgcn_mfma_f32_16x16x32_bf16(a0, bf, acc[0][ct], 0, 0, 0);
            acc[1][ct] = __builtin_amdgcn_mfma_f32_16x16x32_bf16(a1, bf, acc[1][ct], 0, 0, 0);
        }
    }
    // C/D layout (m89-verified): col = lane&15, row = (lane>>4)*4 + reg
    const int colb = l & 15;
    const int rowoff = (l >> 4) * 4;
    #pragma unroll
    for (int rt = 0; rt < 2; ++rt) {
        #pragma unroll
        for (int j = 0; j < 4; ++j) {
            const int row = rbase + rt * 16 + rowoff + j;
            if (row < M) {
                #pragma unroll
                for (int ct = 0; ct < 8; ++ct)
                    Yp[(size_t)row * 128 + ct * 16 + colb] = acc[rt][ct][j];
            }
        }
    }
}

// ---------------- layer-0 aggregate from the bf16 combo table -> bf16 X ---------
__global__ __launch_bounds__(256) void aggregate0_kernel(
        const unsigned short* __restrict__ Ycb, const int* __restrict__ oc,
        const int* __restrict__ combo, const int* __restrict__ offsets,
        const float* __restrict__ b, unsigned short* __restrict__ Xn) {
    int idx = blockIdx.x * 256 + threadIdx.x;
    int node = idx >> 5;
    int c = (idx & 31) * 4;
    if (node >= N_NODES) return;
    const int beg = offsets[node], end = offsets[node + 1];
    float ax = 0.f, ay = 0.f, az = 0.f, aw = 0.f;
    float gx = 0.f, gy = 0.f, gz = 0.f, gw = 0.f;
    int j = beg;
    for (; j + 3 < end; j += 4) {
        int q0 = oc[j] >> 16, q1 = oc[j + 1] >> 16;
        int q2 = oc[j + 2] >> 16, q3 = oc[j + 3] >> 16;
        ushort4 u0 = *(const ushort4*)&Ycb[(size_t)q0 * 256 + c];
        ushort4 u1 = *(const ushort4*)&Ycb[(size_t)q1 * 256 + c];
        ushort4 u2 = *(const ushort4*)&Ycb[(size_t)q2 * 256 + c];
        ushort4 u3 = *(const ushort4*)&Ycb[(size_t)q3 * 256 + c];
        ax += b2f(u0.x) + b2f(u1.x); ay += b2f(u0.y) + b2f(u1.y);
        az += b2f(u0.z) + b2f(u1.z); aw += b2f(u0.w) + b2f(u1.w);
        gx += b2f(u2.x) + b2f(u3.x); gy += b2f(u2.y) + b2f(u3.y);
        gz += b2f(u2.z) + b2f(u3.z); gw += b2f(u2.w) + b2f(u3.w);
    }
    for (; j < end; ++j) {
        int q0 = oc[j] >> 16;
        ushort4 u0 = *(const ushort4*)&Ycb[(size_t)q0 * 256 + c];
        ax += b2f(u0.x); ay += b2f(u0.y); az += b2f(u0.z); aw += b2f(u0.w);
    }
    float sx = ax + gx, sy = ay + gy, sz = az + gz, sw = aw + gw;
    const float inv = 1.0f / fmaxf((float)(end - beg), 1.0f);
    ushort4 ur = *(const ushort4*)&Ycb[(size_t)combo[node] * 256 + 128 + c];
    float4 bb = *(const float4*)&b[c];
    ushort4 o;
    o.x = f2b(eluf(fmaf(sx, inv, bb.x) + b2f(ur.x)));
    o.y = f2b(eluf(fmaf(sy, inv, bb.y) + b2f(ur.y)));
    o.z = f2b(eluf(fmaf(sz, inv, bb.z) + b2f(ur.z)));
    o.w = f2b(eluf(fmaf(sw, inv, bb.w) + b2f(ur.w)));
    *(ushort4*)&Xn[(size_t)node * 128 + c] = o;
}

// ---------------- layers 1/2 aggregate: gather bf16 rel, stream f32 root -> bf16 X
__global__ __launch_bounds__(256) void aggregate_kernel(
        const unsigned short* __restrict__ Ybrel, const float* __restrict__ Yroot,
        const int* __restrict__ oc, const int* __restrict__ offsets,
        const float* __restrict__ b, unsigned short* __restrict__ Xn) {
    int idx = blockIdx.x * 256 + threadIdx.x;
    int node = idx >> 5;
    int c = (idx & 31) * 4;
    if (node >= N_NODES) return;
    const int beg = offsets[node], end = offsets[node + 1];
    float ax = 0.f, ay = 0.f, az = 0.f, aw = 0.f;
    float gx = 0.f, gy = 0.f, gz = 0.f, gw = 0.f;
    int j = beg;
    for (; j + 3 < end; j += 4) {
        int s0 = oc[j] & 0xFFFF, s1 = oc[j + 1] & 0xFFFF;
        int s2 = oc[j + 2] & 0xFFFF, s3 = oc[j + 3] & 0xFFFF;
        ushort4 u0 = *(const ushort4*)&Ybrel[(size_t)s0 * 128 + c];
        ushort4 u1 = *(const ushort4*)&Ybrel[(size_t)s1 * 128 + c];
        ushort4 u2 = *(const ushort4*)&Ybrel[(size_t)s2 * 128 + c];
        ushort4 u3 = *(const ushort4*)&Ybrel[(size_t)s3 * 128 + c];
        ax += b2f(u0.x) + b2f(u1.x); ay += b2f(u0.y) + b2f(u1.y);
        az += b2f(u0.z) + b2f(u1.z); aw += b2f(u0.w) + b2f(u1.w);
        gx += b2f(u2.x) + b2f(u3.x); gy += b2f(u2.y) + b2f(u3.y);
        gz += b2f(u2.z) + b2f(u3.z); gw += b2f(u2.w) + b2f(u3.w);
    }
    for (; j < end; ++j) {
        int s0 = oc[j] & 0xFFFF;
        ushort4 u0 = *(const ushort4*)&Ybrel[(size_t)s0 * 128 + c];
        ax += b2f(u0.x); ay += b2f(u0.y); az += b2f(u0.z); aw += b2f(u0.w);
    }
    float sx = ax + gx, sy = ay + gy, sz = az + gz, sw = aw + gw;
    const float inv = 1.0f / fmaxf((float)(end - beg), 1.0f);
    float4 yr = *(const float4*)&Yroot[(size_t)node * 128 + c];
    float4 bb = *(const float4*)&b[c];
    ushort4 o;
    o.x = f2b(eluf(fmaf(sx, inv, bb.x) + yr.x));
    o.y = f2b(eluf(fmaf(sy, inv, bb.y) + yr.y));
    o.z = f2b(eluf(fmaf(sz, inv, bb.z) + yr.z));
    o.w = f2b(eluf(fmaf(sw, inv, bb.w) + yr.w));
    *(ushort4*)&Xn[(size_t)node * 128 + c] = o;
}

// ---------------- convert: f32 rel plane -> bf16 rel plane ----------------
__global__ __launch_bounds__(256) void conv_kernel(const float* __restrict__ Yf,
        unsigned short* __restrict__ Yb) {
    int i = blockIdx.x * 256 + threadIdx.x;      // over N*128/8 = 800000
    if (i >= N_NODES * 16) return;
    float4 a = ((const float4*)Yf)[(size_t)i * 2];
    float4 b = ((const float4*)Yf)[(size_t)i * 2 + 1];
    uint4 w;
    w.x = (unsigned int)f2b(a.x) | ((unsigned int)f2b(a.y) << 16);
    w.y = (unsigned int)f2b(a.z) | ((unsigned int)f2b(a.w) << 16);
    w.z = (unsigned int)f2b(b.x) | ((unsigned int)f2b(b.y) << 16);
    w.w = (unsigned int)f2b(b.z) | ((unsigned int)f2b(b.w) << 16);
    ((uint4*)Yb)[i] = w;
}

// ---------------- output head: out = X(bf16) @ w_out + b_out ----------------
__global__ __launch_bounds__(256) void out_kernel(const unsigned short* __restrict__ X,
        const float* __restrict__ W, const float* __restrict__ bo,
        float* __restrict__ out, int M) {
    __shared__ float Ws[128 * 32];
    const int tid = threadIdx.x;
    #pragma unroll
    for (int o = tid * 4; o < 4096; o += 1024)
        *(float4*)&Ws[o] = *(const float4*)&W[o];
    __syncthreads();
    const int row = blockIdx.x * 32 + (tid >> 3);
    const int col = (tid & 7) * 4;
    if (row >= M) return;
    float a0 = 0.f, a1 = 0.f, a2 = 0.f, a3 = 0.f;
    for (int k8 = 0; k8 < 16; ++k8) {
        ushort4 xl = *(const ushort4*)&X[(size_t)row * 128 + k8 * 8];
        ushort4 xh = *(const ushort4*)&X[(size_t)row * 128 + k8 * 8 + 4];
        float xa[8] = {b2f(xl.x), b2f(xl.y), b2f(xl.z), b2f(xl.w),
                       b2f(xh.x), b2f(xh.y), b2f(xh.z), b2f(xh.w)};
        #pragma unroll
        for (int j = 0; j < 8; ++j) {
            float4 wv = *(const float4*)&Ws[(k8 * 8 + j) * 32 + col];
            a0 = fmaf(xa[j], wv.x, a0);
            a1 = fmaf(xa[j], wv.y, a1);
            a2 = fmaf(xa[j], wv.z, a2);
            a3 = fmaf(xa[j], wv.w, a3);
        }
    }
    float4 bb = *(const float4*)&bo[col];
    *(float4*)&out[(size_t)row * 32 + col] =
        make_float4(a0 + bb.x, a1 + bb.y, a2 + bb.z, a3 + bb.w);
}

extern "C" void kernel_launch(void* const* d_in, const int* in_sizes, int n_in,
                              void* d_out, int out_size, void* d_ws, size_t ws_size,
                              hipStream_t stream) {
    const int* x        = (const int*)d_in[0];
    const int* ei       = (const int*)d_in[1];
    const float* e0     = (const float*)d_in[2];
    const float* e1     = (const float*)d_in[3];
    const float* e2     = (const float*)d_in[4];
    const float* w_rel0 = (const float*)d_in[5];
    const float* w_root0= (const float*)d_in[6];
    const float* b0     = (const float*)d_in[7];
    const float* w_rel1 = (const float*)d_in[8];
    const float* w_root1= (const float*)d_in[9];
    const float* b1     = (const float*)d_in[10];
    const float* w_rel2 = (const float*)d_in[11];
    const float* w_root2= (const float*)d_in[12];
    const float* b2     = (const float*)d_in[13];
    const float* w_out  = (const float*)d_in[14];
    const float* b_out  = (const float*)d_in[15];
    float* out = (float*)d_out;

    const int N = N_NODES, E = N_EDGES;
    // workspace layout (~81.3 MB, 16B-aligned)
    char* base = (char*)d_ws;
    float*          Yrel = (float*)base;                         // [N,128] f32
    float*          Yroot= (float*)(base + 25600000);            // [N,128] f32
    unsigned short* Xb   = (unsigned short*)(base + 51200000);   // [N,128] bf16
    unsigned short* H    = (unsigned short*)(base + 64000000);   // [N,128] bf16
    int*            oc   = (int*)(base + 76800000);              // [E] packed
    unsigned short* Bp   = (unsigned short*)(base + 80000000);   // [4][4][8][64][8] bf16
    float*          P    = (float*)(base + 80131072);            // [24,256] f32
    unsigned short* Ycb  = (unsigned short*)(base + 80155648);   // [512,256] bf16
    int*            cnt     = (int*)(base + 80417792);           // [N]
    int*            offsets = cnt + N;                           // [N+1]
    int*            pos     = offsets + N + 1;                   // [N]
    int*            combo   = pos + N;                           // [N]
    int*            part    = combo + N;                         // [SCAN_NBLK]

    const int* src = ei;
    const int* tgt = ei + E;

    // --- CSR build + combo ids ---
    hipMemsetAsync(cnt, 0, N * sizeof(int), stream);
    count_combo_kernel<<<(E + 255) / 256, 256, 0, stream>>>(tgt, x, cnt, combo, E);
    scan_part_kernel<<<SCAN_NBLK, 256, 0, stream>>>(cnt, part);
    scan_top_kernel<<<1, 256, 0, stream>>>(part);
    scan_final_kernel<<<SCAN_NBLK, 256, 0, stream>>>(cnt, part, offsets, pos);
    fill_kernel<<<(E + 255) / 256, 256, 0, stream>>>(src, tgt, combo, pos, oc);

    // --- layer-0 combo table (separable) + weight pack ---
    ptab_kernel<<<24, 256, 0, stream>>>(e0, e1, e2, w_rel0, w_root0, P);
    ytab_kernel<<<512, 256, 0, stream>>>(P, Ycb);
    pack_kernel<<<128, 64, 0, stream>>>(w_rel1, w_root1, w_rel2, w_root2, Bp);

    const int agg_grid = (N * 32 + 255) / 256;
    const int conv_grid = (N * 16 + 255) / 256;
    dim3 ggrid((N + 127) / 128, 2);

    // --- layer 0 -> Xb ---
    aggregate0_kernel<<<agg_grid, 256, 0, stream>>>(Ycb, oc, combo, offsets, b0, Xb);

    // --- layer 1: Xb -> (Yrel, Yroot) -> H -> Xb ---
    gemm_mfma<<<ggrid, 256, 0, stream>>>(Xb, Bp, 0, Yrel, Yroot, N);
    conv_kernel<<<conv_grid, 256, 0, stream>>>(Yrel, H);
    aggregate_kernel<<<agg_grid, 256, 0, stream>>>(H, Yroot, oc, offsets, b1, Xb);

    // --- layer 2 ---
    gemm_mfma<<<ggrid, 256, 0, stream>>>(Xb, Bp, 2, Yrel, Yroot, N);
    conv_kernel<<<conv_grid, 256, 0, stream>>>(Yrel, H);
    aggregate_kernel<<<agg_grid, 256, 0, stream>>>(H, Yroot, oc, offsets, b2, Xb);

    out_kernel<<<(N + 31) / 32, 256, 0, stream>>>(Xb, w_out, b_out, out, N);
}